// Round 1
// baseline (1311.023 us; speedup 1.0000x reference)
//
#include <hip/hip_runtime.h>

// Segment-sum: edges [TOTAL_EDGES, 128] fp32 -> out [NUM_GRAPHS, 128] fp32.
// Per-graph edge ranges are contiguous (indices = repeat(arange, n_edge)),
// so graph g owns rows [offset[g], offset[g]+n_edge[g]). Memory-bound:
// 1.07 GB read / ~170 us floor at 6.3 TB/s.

#define DV4 32  // 128 features = 32 float4 per row

// Exclusive scan of n_edge (num_graphs <= 1024) -> row offsets.
__global__ void scan_offsets_kernel(const int* __restrict__ n_edge,
                                    int num_graphs,
                                    long long* __restrict__ offsets) {
    __shared__ int s[1024];
    int t = threadIdx.x;
    s[t] = (t < num_graphs) ? n_edge[t] : 0;
    __syncthreads();
    // Hillis-Steele inclusive scan
    for (int off = 1; off < 1024; off <<= 1) {
        int add = (t >= off) ? s[t - off] : 0;
        __syncthreads();
        s[t] += add;
        __syncthreads();
    }
    if (t < num_graphs) {
        offsets[t] = (t == 0) ? 0LL : (long long)s[t - 1];
    }
}

// One block (256 threads = 4 waves... actually 8 half-rows) per graph.
// lane (tid&31) -> float4 column; rowg (tid>>5) -> row stride of 8.
__global__ __launch_bounds__(256) void agg_kernel(
        const float4* __restrict__ edges,
        const long long* __restrict__ offsets,
        const int* __restrict__ n_edge,
        float4* __restrict__ out) {
    const int g    = blockIdx.x;
    const int lane = threadIdx.x & 31;
    const int rowg = threadIdx.x >> 5;

    const long long base = offsets[g] * (long long)DV4;
    const int ne = n_edge[g];

    float4 acc = make_float4(0.f, 0.f, 0.f, 0.f);

    // Main unrolled loop: 4 rows in flight per thread per iteration.
    int r = rowg;
    const int step = 8;
    for (; r + 3 * step < ne; r += 4 * step) {
        float4 v0 = edges[base + (long long)(r + 0 * step) * DV4 + lane];
        float4 v1 = edges[base + (long long)(r + 1 * step) * DV4 + lane];
        float4 v2 = edges[base + (long long)(r + 2 * step) * DV4 + lane];
        float4 v3 = edges[base + (long long)(r + 3 * step) * DV4 + lane];
        acc.x += v0.x; acc.y += v0.y; acc.z += v0.z; acc.w += v0.w;
        acc.x += v1.x; acc.y += v1.y; acc.z += v1.z; acc.w += v1.w;
        acc.x += v2.x; acc.y += v2.y; acc.z += v2.z; acc.w += v2.w;
        acc.x += v3.x; acc.y += v3.y; acc.z += v3.z; acc.w += v3.w;
    }
    for (; r < ne; r += step) {
        float4 v = edges[base + (long long)r * DV4 + lane];
        acc.x += v.x; acc.y += v.y; acc.z += v.z; acc.w += v.w;
    }

    // 8-way reduction across row-groups via LDS.
    __shared__ float4 s[8][DV4];
    s[rowg][lane] = acc;
    __syncthreads();
    if (rowg == 0) {
        float4 t = s[0][lane];
        #pragma unroll
        for (int i = 1; i < 8; ++i) {
            float4 v = s[i][lane];
            t.x += v.x; t.y += v.y; t.z += v.z; t.w += v.w;
        }
        out[(long long)g * DV4 + lane] = t;
    }
}

extern "C" void kernel_launch(void* const* d_in, const int* in_sizes, int n_in,
                              void* d_out, int out_size, void* d_ws, size_t ws_size,
                              hipStream_t stream) {
    const float* edges  = (const float*)d_in[0];
    const int*   n_edge = (const int*)d_in[1];
    const int num_graphs = in_sizes[1];

    long long* offsets = (long long*)d_ws;  // num_graphs * 8 bytes

    scan_offsets_kernel<<<1, 1024, 0, stream>>>(n_edge, num_graphs, offsets);
    agg_kernel<<<num_graphs, 256, 0, stream>>>(
        (const float4*)edges, offsets, n_edge, (float4*)d_out);
}